// Round 13
// baseline (196.644 us; speedup 1.0000x reference)
//
#include <hip/hip_runtime.h>
#include <cmath>

typedef __attribute__((ext_vector_type(8))) __bf16 bf16x8;
typedef __attribute__((ext_vector_type(4))) __bf16 bf16x4;
typedef __attribute__((ext_vector_type(4))) float f32x4;
typedef __attribute__((ext_vector_type(2))) unsigned int u32x2;
typedef __attribute__((ext_vector_type(4))) unsigned int u32x4;

#define MFMA16(a, b, c) __builtin_amdgcn_mfma_f32_16x16x32_bf16(a, b, c, 0, 0, 0)

// 0.125 (1/sqrt(HD)) * log2(e): folded into Q projection so softmax can use exp2.
#define QSCALE 0.1803368801111601f

__device__ __forceinline__ void gload_lds16(void* lds, const void* g) {
    __builtin_amdgcn_global_load_lds(
        (const __attribute__((address_space(1))) unsigned int*)g,
        (__attribute__((address_space(3))) unsigned int*)lds, 16, 0, 0);
}

// Stage PASSES*4096 bytes of a [rows][64 bf16] tile (row = 128B) into LDS,
// XOR-swizzled: LDS linear byte i holds tile byte i ^ ((row&7)<<4).
template <int PASSES>
__device__ __forceinline__ void stage_tile(char* lds, const __bf16* src,
                                           int stride_elems, int tid) {
    const char* s = (const char*)src;
    char* wbase = lds + (tid >> 6) * 1024;
#pragma unroll
    for (int p = 0; p < PASSES; ++p) {
        int i = p * 4096 + tid * 16;
        int row = i >> 7;
        int j = i ^ ((row & 7) << 4);
        gload_lds16(wbase + p * 4096,
                    s + (size_t)row * stride_elems * 2 + (j & 127));
    }
}

// Read one bf16x8 MFMA fragment from a swizzled [rows][64] tile.
__device__ __forceinline__ bf16x8 frag_ld(const char* tile, int row, int kb) {
    int addr = (row << 7) + kb;
    addr ^= ((row & 7) << 4);
    return *(const bf16x8*)(tile + addr);
}

// ---------------- cast fp32 -> bf16 (query/key/value) ----------------
__global__ __launch_bounds__(256) void cast_x(const float* __restrict__ q,
                                              const float* __restrict__ k,
                                              const float* __restrict__ v,
                                              __bf16* __restrict__ X) {
    int z = blockIdx.z;
    const float* src = (z == 0) ? q : (z == 1) ? k : v;
    __bf16* dst = X + (size_t)z * 4194304;
    int i = blockIdx.x * 256 + threadIdx.x;
    float4 f = ((const float4*)src)[i];
    bf16x4 o = {(__bf16)f.x, (__bf16)f.y, (__bf16)f.z, (__bf16)f.w};
    ((bf16x4*)dst)[i] = o;
}

// ---------------- mask -> additive float (8192 = B*L elements) ----------------
__global__ __launch_bounds__(256) void maskprep(const int* __restrict__ mask,
                                                float* __restrict__ mf) {
    int i = blockIdx.x * 256 + threadIdx.x;
    mf[i] = mask[i] ? 0.f : -1e30f;
}

// ---------------- transpose weights fp32[512][512] -> bf16 Wt[n][k] ----------------
__global__ __launch_bounds__(256) void wtrans(const float* __restrict__ Wq,
                                              const float* __restrict__ Wk,
                                              const float* __restrict__ Wv,
                                              const float* __restrict__ Wo,
                                              __bf16* __restrict__ Wt) {
    int z = blockIdx.z;
    const float* W = (z == 0) ? Wq : (z == 1) ? Wk : (z == 2) ? Wv : Wo;
    __bf16* out = Wt + (size_t)z * 262144;
    __shared__ float t[32][33];
    int r = threadIdx.x >> 5, cc = threadIdx.x & 31;
    int k0 = blockIdx.y * 32, n0 = blockIdx.x * 32;
#pragma unroll
    for (int rr = 0; rr < 4; ++rr)
        t[r + rr * 8][cc] = W[(size_t)(k0 + r + rr * 8) * 512 + n0 + cc];
    __syncthreads();
#pragma unroll
    for (int rr = 0; rr < 4; ++rr)
        out[(size_t)(n0 + r + rr * 8) * 512 + k0 + cc] = (__bf16)t[cc][r + rr * 8];
}

// ---------------- 128x128 tiled bf16 GEMM: out = A(8192x512) * W + bias ----------------
__global__ __launch_bounds__(256) void gemm_qkv(
    const __bf16* __restrict__ X, const __bf16* __restrict__ Wt,
    const float* __restrict__ b0, const float* __restrict__ b1,
    const float* __restrict__ b2, __bf16* __restrict__ Qo,
    __bf16* __restrict__ Ko, __bf16* __restrict__ Vto, int modeBase,
    float* __restrict__ outF) {
    __shared__ char smem[32768];
    char* At = smem;
    char* Bt = smem + 16384;
    int z = blockIdx.z;
    int mode = modeBase + z;
    const __bf16* A = X + (size_t)z * (8192 * 512);
    const __bf16* B = Wt + (size_t)z * (512 * 512);
    const float* bias = (mode == 1) ? b1 : (mode == 2) ? b2 : b0;

    int tid = threadIdx.x;
    int lane = tid & 63, wid = tid >> 6;
    int c = lane & 15, g = lane >> 4;
    int wm = (wid >> 1) * 64, wn = (wid & 1) * 64;
    int m0 = blockIdx.x * 128, n0 = blockIdx.y * 128;

    f32x4 zero = {0.f, 0.f, 0.f, 0.f};
    f32x4 acc[4][4];
#pragma unroll
    for (int i = 0; i < 4; ++i)
#pragma unroll
        for (int j = 0; j < 4; ++j) acc[i][j] = zero;

    for (int k0 = 0; k0 < 512; k0 += 64) {
        __syncthreads();
        stage_tile<4>(At, A + (size_t)m0 * 512 + k0, 512, tid);
        stage_tile<4>(Bt, B + (size_t)n0 * 512 + k0, 512, tid);
        __syncthreads();
#pragma unroll
        for (int ks = 0; ks < 2; ++ks) {
            bf16x8 af[4], bff[4];
#pragma unroll
            for (int mt = 0; mt < 4; ++mt)
                af[mt] = frag_ld(At, wm + mt * 16 + c, g * 16 + ks * 64);
#pragma unroll
            for (int nt = 0; nt < 4; ++nt)
                bff[nt] = frag_ld(Bt, wn + nt * 16 + c, g * 16 + ks * 64);
#pragma unroll
            for (int mt = 0; mt < 4; ++mt)
#pragma unroll
                for (int nt = 0; nt < 4; ++nt)
                    acc[mt][nt] = MFMA16(af[mt], bff[nt], acc[mt][nt]);
        }
    }

    float bv[4];
#pragma unroll
    for (int nt = 0; nt < 4; ++nt) bv[nt] = bias[n0 + wn + nt * 16 + c];
    float sc = (mode == 0) ? QSCALE : 1.0f;

    if (mode == 3) {
#pragma unroll
        for (int mt = 0; mt < 4; ++mt)
#pragma unroll
            for (int nt = 0; nt < 4; ++nt)
#pragma unroll
                for (int j = 0; j < 4; ++j) {
                    int m = m0 + wm + mt * 16 + g * 4 + j;
                    int n = n0 + wn + nt * 16 + c;
                    outF[(size_t)m * 512 + n] = acc[mt][nt][j] + bv[nt];
                }
    } else if (mode == 2) {
#pragma unroll
        for (int mt = 0; mt < 4; ++mt)
#pragma unroll
            for (int nt = 0; nt < 4; ++nt) {
                int m = m0 + wm + mt * 16 + g * 4;
                int n = n0 + wn + nt * 16 + c;
                int b = m >> 12, l = m & 4095, hh = n >> 6, hd = n & 63;
                bf16x4 v;
#pragma unroll
                for (int j = 0; j < 4; ++j)
                    v[j] = (__bf16)(acc[mt][nt][j] + bv[nt]);
                *(bf16x4*)(Vto + ((size_t)((b * 8 + hh) * 64 + hd)) * 4096 + l) = v;
            }
    } else {
        __bf16* dst = (mode == 0) ? Qo : Ko;
#pragma unroll
        for (int mt = 0; mt < 4; ++mt)
#pragma unroll
            for (int nt = 0; nt < 4; ++nt)
#pragma unroll
                for (int j = 0; j < 4; ++j) {
                    int m = m0 + wm + mt * 16 + g * 4 + j;
                    int n = n0 + wn + nt * 16 + c;
                    int b = m >> 12, l = m & 4095, hh = n >> 6, hd = n & 63;
                    dst[((size_t)((b * 8 + hh) * 4096 + l)) * 64 + hd] =
                        (__bf16)((acc[mt][nt][j] + bv[nt]) * sc);
                }
    }
}

// ---------------- flash attention ----------------------------------------
// EXACTLY R10's verified kernel (passed, absmax 4.88e-4) plus
// sched_barrier(0) pins: one right after each __syncthreads (so the
// STAGE/LDMASK vmem issues stay at the top of the iteration instead of
// being sunk to the bottom, where the next barrier's vmcnt drain would
// serialize on them) and one after the STAGE/LDMASK cluster.
// K ring 2-deep, V ring 3-deep, staging 2-ahead, mask in registers.
__global__ __launch_bounds__(256) void attn_fa(const __bf16* __restrict__ Q,
                                               const __bf16* __restrict__ K,
                                               const __bf16* __restrict__ Vt,
                                               const float* __restrict__ mf,
                                               __bf16* __restrict__ O) {
    // K ring: [0, 16384) = 2 x 8192 ; V ring: [16384, 40960) = 3 x 8192
    __shared__ char smem[40960];

    int tid = threadIdx.x, lane = tid & 63, wid = tid >> 6;
    int c = lane & 15, g = lane >> 4;

    // XCD-chunked swizzle: 512 blocks, 64 per XCD -> each XCD sees 2 bh values.
    int sw = (blockIdx.x & 7) * 64 + (blockIdx.x >> 3);
    int bh = sw >> 5, b = bh >> 3, h = bh & 7;
    int q0 = (sw & 31) * 128;

    const __bf16* Qb = Q + (size_t)bh * 4096 * 64;
    const __bf16* Kb = K + (size_t)bh * 4096 * 64;
    const __bf16* Vb = Vt + (size_t)bh * 64 * 4096;
    const float* mfb = mf + (size_t)b * 4096;
    int qw = q0 + wid * 32;

    // Q fragments (B operand of S^T = K Q^T)
    bf16x8 qf[2][2];
#pragma unroll
    for (int nq = 0; nq < 2; ++nq)
#pragma unroll
        for (int ks = 0; ks < 2; ++ks)
            qf[nq][ks] = *(const bf16x8*)(Qb + (size_t)(qw + nq * 16 + c) * 64 +
                                          g * 8 + ks * 32);

    // staging bases (pre-swizzled global source, linear LDS dest)
    int rowp = tid >> 3;                               // 0..31
    int jlow = ((tid & 7) << 4) ^ ((rowp & 7) << 4);   // p-independent
    const char* kB0 = (const char*)Kb + rowp * 128 + jlow;
    const char* kB1 = (const char*)Kb + (32 + rowp) * 128 + jlow;
    const char* vB0 = (const char*)Vb + rowp * 8192 + jlow;
    const char* vB1 = (const char*)Vb + (32 + rowp) * 8192 + jlow;
    int woff = (tid >> 6) * 1024;

#define STAGE(t)                                                              \
    {                                                                         \
        int uk_ = (t) & 1, uv_ = (t) % 3;                                     \
        size_t ko_ = (size_t)(t) * 8192, vo_ = (size_t)(t) * 128;             \
        gload_lds16(smem + uk_ * 8192 + woff, kB0 + ko_);                     \
        gload_lds16(smem + uk_ * 8192 + 4096 + woff, kB1 + ko_);              \
        gload_lds16(smem + 16384 + uv_ * 8192 + woff, vB0 + vo_);             \
        gload_lds16(smem + 16384 + uv_ * 8192 + 4096 + woff, vB1 + vo_);      \
    }

    f32x4 zero = {0.f, 0.f, 0.f, 0.f};
    f32x4 acc[4][2];  // acc[hd-tile][q-tile]: row=hd, col=q
#pragma unroll
    for (int i = 0; i < 4; ++i)
#pragma unroll
        for (int j = 0; j < 2; ++j) acc[i][j] = zero;
    f32x4 rsum4[2] = {zero, zero};  // per-lane partial row sums

    // mask prefetch: per lane 16 values (kv = t*64 + mt*16 + g*4 + j)
    auto LDMASK = [&](int t, f32x4(&mv)[4]) {
#pragma unroll
        for (int mt = 0; mt < 4; ++mt)
            mv[mt] = *(const f32x4*)(mfb + t * 64 + mt * 16 + g * 4);
    };

    // S^T(t) = mask + K(t) Q^T (mask seeds the MFMA accumulator)
    auto QKT = [&](int t, f32x4(&s)[4][2], const f32x4(&mv)[4]) {
        const char* Ktc = smem + (t & 1) * 8192;
#pragma unroll
        for (int mt = 0; mt < 4; ++mt) {
            s[mt][0] = mv[mt];
            s[mt][1] = mv[mt];
        }
        __builtin_amdgcn_s_setprio(1);
#pragma unroll
        for (int ks = 0; ks < 2; ++ks) {
            bf16x8 kf[4];
#pragma unroll
            for (int mt = 0; mt < 4; ++mt)
                kf[mt] = frag_ld(Ktc, mt * 16 + c, g * 16 + ks * 64);
#pragma unroll
            for (int mt = 0; mt < 4; ++mt)
#pragma unroll
                for (int nq = 0; nq < 2; ++nq)
                    s[mt][nq] = MFMA16(kf[mt], qf[nq][ks], s[mt][nq]);
        }
        __builtin_amdgcn_s_setprio(0);
    };

    // softmax(s) in-register + PV(t): x^T += V(t)^T P^T
    auto SMPV = [&](int t, f32x4(&s)[4][2]) {
        const char* Vtc = smem + 16384 + (t % 3) * 8192;
        unsigned int pku[4][2][2];
#pragma unroll
        for (int mt = 0; mt < 4; ++mt)
#pragma unroll
            for (int nq = 0; nq < 2; ++nq) {
                f32x4 p;
#pragma unroll
                for (int j = 0; j < 4; ++j)
                    p[j] = __builtin_amdgcn_exp2f(s[mt][nq][j]);
                rsum4[nq] += p;
                bf16x4 pw = {(__bf16)p[0], (__bf16)p[1], (__bf16)p[2],
                             (__bf16)p[3]};
                u32x2 u2 = __builtin_bit_cast(u32x2, pw);
                pku[mt][nq][0] = u2.x;
                pku[mt][nq][1] = u2.y;
            }
#pragma unroll
        for (int ks2 = 0; ks2 < 2; ++ks2) {
            bf16x8 vf[4];
#pragma unroll
            for (int mh = 0; mh < 4; ++mh)
                vf[mh] = frag_ld(Vtc, mh * 16 + c, g * 16 + ks2 * 64);
            bf16x8 pf[2];
#pragma unroll
            for (int nq = 0; nq < 2; ++nq) {
                unsigned int a0 = pku[2 * ks2][nq][0];
                unsigned int a1 = pku[2 * ks2][nq][1];
                unsigned int b0 = pku[2 * ks2 + 1][nq][0];
                unsigned int b1 = pku[2 * ks2 + 1][nq][1];
                asm("v_permlane32_swap_b32 %0, %1" : "+v"(a0), "+v"(b0));
                asm("v_permlane32_swap_b32 %0, %1" : "+v"(a1), "+v"(b1));
                asm("v_permlane16_swap_b32 %0, %1" : "+v"(a0), "+v"(b0));
                asm("v_permlane16_swap_b32 %0, %1" : "+v"(a1), "+v"(b1));
                u32x4 pv = {a0, a1, b0, b1};
                pf[nq] = __builtin_bit_cast(bf16x8, pv);
            }
            __builtin_amdgcn_s_setprio(1);
#pragma unroll
            for (int mh = 0; mh < 4; ++mh)
#pragma unroll
                for (int nq = 0; nq < 2; ++nq)
                    acc[mh][nq] = MFMA16(vf[mh], pf[nq], acc[mh][nq]);
            __builtin_amdgcn_s_setprio(0);
        }
    };

    f32x4 mvA[4], mvB[4];
    STAGE(0);
    STAGE(1);
    LDMASK(0, mvA);
    LDMASK(1, mvB);
    __syncthreads();
    __builtin_amdgcn_sched_barrier(0);

    f32x4 sA[4][2], sB[4][2];
    QKT(0, sA, mvA);

#pragma unroll 1
    for (int tt = 0; tt < 32; ++tt) {
        int t0 = 2 * tt, t1 = 2 * tt + 1;
        // ---- half-iter t0 ----
        __syncthreads();
        __builtin_amdgcn_sched_barrier(0);
        if (t0 <= 61) {
            STAGE(t0 + 2);
            LDMASK(t0 + 2, mvA);
        }
        __builtin_amdgcn_sched_barrier(0);
        if (t0 < 63) QKT(t0 + 1, sB, mvB);
        SMPV(t0, sA);
        // ---- half-iter t1 ----
        __syncthreads();
        __builtin_amdgcn_sched_barrier(0);
        if (t1 <= 61) {
            STAGE(t1 + 2);
            LDMASK(t1 + 2, mvB);
        }
        __builtin_amdgcn_sched_barrier(0);
        if (t1 < 63) QKT(t1 + 1, sA, mvA);
        SMPV(t1, sB);
    }
#undef STAGE

    // final L reduce: horizontal sum + 2 shfl over g-groups
    float rl[2];
#pragma unroll
    for (int nq = 0; nq < 2; ++nq) {
        float r = (rsum4[nq][0] + rsum4[nq][1]) + (rsum4[nq][2] + rsum4[nq][3]);
        r += __shfl_xor(r, 16, 64);
        r += __shfl_xor(r, 32, 64);
        rl[nq] = 1.0f / r;
    }

    __syncthreads();  // full drain before reusing LDS for O staging

    // normalize, stage O tile [128 q][64 hd] in smem (pitch 144), coalesced store
    char* Pw = smem + wid * 4608;
#pragma unroll
    for (int mh = 0; mh < 4; ++mh)
#pragma unroll
        for (int nq = 0; nq < 2; ++nq) {
            bf16x4 o;
#pragma unroll
            for (int j = 0; j < 4; ++j) o[j] = (__bf16)(acc[mh][nq][j] * rl[nq]);
            *(bf16x4*)(Pw + (nq * 16 + c) * 144 + mh * 32 + g * 8) = o;
        }
    __syncthreads();
#pragma unroll
    for (int p = 0; p < 4; ++p) {
        int i = p * 4096 + tid * 16;
        int row = i >> 7, colb = i & 127;
        bf16x8 v = *(const bf16x8*)(smem + row * 144 + colb);
        *(bf16x8*)(O + ((size_t)(b * 4096 + q0 + row)) * 512 + h * 64 +
                   colb / 2) = v;
    }
}

extern "C" void kernel_launch(void* const* d_in, const int* in_sizes, int n_in,
                              void* d_out, int out_size, void* d_ws,
                              size_t ws_size, hipStream_t stream) {
    const float* query = (const float*)d_in[0];
    const float* key = (const float*)d_in[1];
    const float* value = (const float*)d_in[2];
    const int* mask = (const int*)d_in[3];
    const float* Wq = (const float*)d_in[4];
    const float* bq = (const float*)d_in[5];
    const float* Wk = (const float*)d_in[6];
    const float* bk = (const float*)d_in[7];
    const float* Wv = (const float*)d_in[8];
    const float* bv = (const float*)d_in[9];
    const float* Wo = (const float*)d_in[10];
    const float* bo = (const float*)d_in[11];

    char* ws = (char*)d_ws;
    __bf16* Xbf = (__bf16*)(ws);                  // 25165824 B
    __bf16* Wt = (__bf16*)(ws + 25165824);        // 2097152 B
    __bf16* Qb = (__bf16*)(ws + 27262976);        // 8388608 B
    __bf16* Kb = (__bf16*)(ws + 35651584);        // 8388608 B
    __bf16* Vtb = (__bf16*)(ws + 44040192);       // 8388608 B
    __bf16* Ob = (__bf16*)(ws + 52428800);        // 8388608 B
    float* mfb = (float*)Xbf;  // reuse Xbf region after QKV GEMMs (8192 floats)

    cast_x<<<dim3(4096, 1, 3), 256, 0, stream>>>(query, key, value, Xbf);
    wtrans<<<dim3(16, 16, 4), 256, 0, stream>>>(Wq, Wk, Wv, Wo, Wt);
    gemm_qkv<<<dim3(64, 4, 3), 256, 0, stream>>>(Xbf, Wt, bq, bk, bv, Qb, Kb,
                                                 Vtb, 0, nullptr);
    maskprep<<<dim3(32), 256, 0, stream>>>(mask, mfb);
    attn_fa<<<dim3(512), 256, 0, stream>>>(Qb, Kb, Vtb, mfb, Ob);
    gemm_qkv<<<dim3(64, 4, 1), 256, 0, stream>>>(Ob, Wt + 3 * 262144, bo, bo,
                                                 bo, Qb, Kb, Vtb, 3,
                                                 (float*)d_out);
}

// Round 14
// 141.160 us; speedup vs baseline: 1.3931x; 1.3931x over previous
//
#include <hip/hip_runtime.h>
#include <cmath>

typedef __attribute__((ext_vector_type(8))) __bf16 bf16x8;
typedef __attribute__((ext_vector_type(4))) __bf16 bf16x4;
typedef __attribute__((ext_vector_type(4))) float f32x4;
typedef __attribute__((ext_vector_type(2))) unsigned int u32x2;
typedef __attribute__((ext_vector_type(4))) unsigned int u32x4;

#define MFMA16(a, b, c) __builtin_amdgcn_mfma_f32_16x16x32_bf16(a, b, c, 0, 0, 0)

// 0.125 (1/sqrt(HD)) * log2(e): folded into Q projection so softmax can use exp2.
#define QSCALE 0.1803368801111601f

__device__ __forceinline__ void gload_lds16(void* lds, const void* g) {
    __builtin_amdgcn_global_load_lds(
        (const __attribute__((address_space(1))) unsigned int*)g,
        (__attribute__((address_space(3))) unsigned int*)lds, 16, 0, 0);
}

// Stage PASSES*4096 bytes of a [rows][64 bf16] tile (row = 128B) into LDS,
// XOR-swizzled: LDS linear byte i holds tile byte i ^ ((row&7)<<4).
template <int PASSES>
__device__ __forceinline__ void stage_tile(char* lds, const __bf16* src,
                                           int stride_elems, int tid) {
    const char* s = (const char*)src;
    char* wbase = lds + (tid >> 6) * 1024;
#pragma unroll
    for (int p = 0; p < PASSES; ++p) {
        int i = p * 4096 + tid * 16;
        int row = i >> 7;
        int j = i ^ ((row & 7) << 4);
        gload_lds16(wbase + p * 4096,
                    s + (size_t)row * stride_elems * 2 + (j & 127));
    }
}

// Read one bf16x8 MFMA fragment from a swizzled [rows][64] tile.
__device__ __forceinline__ bf16x8 frag_ld(const char* tile, int row, int kb) {
    int addr = (row << 7) + kb;
    addr ^= ((row & 7) << 4);
    return *(const bf16x8*)(tile + addr);
}

// ---------------- cast fp32 -> bf16 (query/key/value) ----------------
__global__ __launch_bounds__(256) void cast_x(const float* __restrict__ q,
                                              const float* __restrict__ k,
                                              const float* __restrict__ v,
                                              __bf16* __restrict__ X) {
    int z = blockIdx.z;
    const float* src = (z == 0) ? q : (z == 1) ? k : v;
    __bf16* dst = X + (size_t)z * 4194304;
    int i = blockIdx.x * 256 + threadIdx.x;
    float4 f = ((const float4*)src)[i];
    bf16x4 o = {(__bf16)f.x, (__bf16)f.y, (__bf16)f.z, (__bf16)f.w};
    ((bf16x4*)dst)[i] = o;
}

// ---------------- transpose weights fp32[512][512] -> bf16 Wt[n][k] ----------------
__global__ __launch_bounds__(256) void wtrans(const float* __restrict__ Wq,
                                              const float* __restrict__ Wk,
                                              const float* __restrict__ Wv,
                                              const float* __restrict__ Wo,
                                              __bf16* __restrict__ Wt) {
    int z = blockIdx.z;
    const float* W = (z == 0) ? Wq : (z == 1) ? Wk : (z == 2) ? Wv : Wo;
    __bf16* out = Wt + (size_t)z * 262144;
    __shared__ float t[32][33];
    int r = threadIdx.x >> 5, cc = threadIdx.x & 31;
    int k0 = blockIdx.y * 32, n0 = blockIdx.x * 32;
#pragma unroll
    for (int rr = 0; rr < 4; ++rr)
        t[r + rr * 8][cc] = W[(size_t)(k0 + r + rr * 8) * 512 + n0 + cc];
    __syncthreads();
#pragma unroll
    for (int rr = 0; rr < 4; ++rr)
        out[(size_t)(n0 + r + rr * 8) * 512 + k0 + cc] = (__bf16)t[cc][r + rr * 8];
}

// ---------------- 128x128 tiled bf16 GEMM: out = A(8192x512) * W + bias ----------------
__global__ __launch_bounds__(256) void gemm_qkv(
    const __bf16* __restrict__ X, const __bf16* __restrict__ Wt,
    const float* __restrict__ b0, const float* __restrict__ b1,
    const float* __restrict__ b2, __bf16* __restrict__ Qo,
    __bf16* __restrict__ Ko, __bf16* __restrict__ Vto, int modeBase,
    float* __restrict__ outF) {
    __shared__ char smem[32768];
    char* At = smem;
    char* Bt = smem + 16384;
    int z = blockIdx.z;
    int mode = modeBase + z;
    const __bf16* A = X + (size_t)z * (8192 * 512);
    const __bf16* B = Wt + (size_t)z * (512 * 512);
    const float* bias = (mode == 1) ? b1 : (mode == 2) ? b2 : b0;

    int tid = threadIdx.x;
    int lane = tid & 63, wid = tid >> 6;
    int c = lane & 15, g = lane >> 4;
    int wm = (wid >> 1) * 64, wn = (wid & 1) * 64;
    int m0 = blockIdx.x * 128, n0 = blockIdx.y * 128;

    f32x4 zero = {0.f, 0.f, 0.f, 0.f};
    f32x4 acc[4][4];
#pragma unroll
    for (int i = 0; i < 4; ++i)
#pragma unroll
        for (int j = 0; j < 4; ++j) acc[i][j] = zero;

    for (int k0 = 0; k0 < 512; k0 += 64) {
        __syncthreads();
        stage_tile<4>(At, A + (size_t)m0 * 512 + k0, 512, tid);
        stage_tile<4>(Bt, B + (size_t)n0 * 512 + k0, 512, tid);
        __syncthreads();
#pragma unroll
        for (int ks = 0; ks < 2; ++ks) {
            bf16x8 af[4], bff[4];
#pragma unroll
            for (int mt = 0; mt < 4; ++mt)
                af[mt] = frag_ld(At, wm + mt * 16 + c, g * 16 + ks * 64);
#pragma unroll
            for (int nt = 0; nt < 4; ++nt)
                bff[nt] = frag_ld(Bt, wn + nt * 16 + c, g * 16 + ks * 64);
#pragma unroll
            for (int mt = 0; mt < 4; ++mt)
#pragma unroll
                for (int nt = 0; nt < 4; ++nt)
                    acc[mt][nt] = MFMA16(af[mt], bff[nt], acc[mt][nt]);
        }
    }

    float bv[4];
#pragma unroll
    for (int nt = 0; nt < 4; ++nt) bv[nt] = bias[n0 + wn + nt * 16 + c];
    float sc = (mode == 0) ? QSCALE : 1.0f;

    if (mode == 3) {
#pragma unroll
        for (int mt = 0; mt < 4; ++mt)
#pragma unroll
            for (int nt = 0; nt < 4; ++nt)
#pragma unroll
                for (int j = 0; j < 4; ++j) {
                    int m = m0 + wm + mt * 16 + g * 4 + j;
                    int n = n0 + wn + nt * 16 + c;
                    outF[(size_t)m * 512 + n] = acc[mt][nt][j] + bv[nt];
                }
    } else if (mode == 2) {
#pragma unroll
        for (int mt = 0; mt < 4; ++mt)
#pragma unroll
            for (int nt = 0; nt < 4; ++nt) {
                int m = m0 + wm + mt * 16 + g * 4;
                int n = n0 + wn + nt * 16 + c;
                int b = m >> 12, l = m & 4095, hh = n >> 6, hd = n & 63;
                bf16x4 v;
#pragma unroll
                for (int j = 0; j < 4; ++j)
                    v[j] = (__bf16)(acc[mt][nt][j] + bv[nt]);
                *(bf16x4*)(Vto + ((size_t)((b * 8 + hh) * 64 + hd)) * 4096 + l) = v;
            }
    } else {
        __bf16* dst = (mode == 0) ? Qo : Ko;
#pragma unroll
        for (int mt = 0; mt < 4; ++mt)
#pragma unroll
            for (int nt = 0; nt < 4; ++nt)
#pragma unroll
                for (int j = 0; j < 4; ++j) {
                    int m = m0 + wm + mt * 16 + g * 4 + j;
                    int n = n0 + wn + nt * 16 + c;
                    int b = m >> 12, l = m & 4095, hh = n >> 6, hd = n & 63;
                    dst[((size_t)((b * 8 + hh) * 4096 + l)) * 64 + hd] =
                        (__bf16)((acc[mt][nt][j] + bv[nt]) * sc);
                }
    }
}

// ---------------- flash attention ----------------------------------------
// Swapped QK^T (softmax per-lane), static max, P in registers (permlane),
// software-pipelined: QK^T(t+1) issued alongside softmax(t)+PV(t) so MFMA
// overlaps the softmax VALU burst. K ring 3-deep, V ring 4-deep:
//   iter t reads K slot (t+1)%3 and V slot t%4; STAGE(t+3) (after the
//   barrier) writes K slot t%3 (last read as K(t) in iter t-1) and V slot
//   (t+3)%4=(t-1)%4 (last read as V(t-1) in iter t-1) -> no collision.
// vmcnt(0)+barrier at iter top: tile t+2 (staged one iter earlier, ~2.5K cy
// in flight) is drained; all slots <= t+2 valid for every wave.
__global__ __launch_bounds__(256) void attn_fa(const __bf16* __restrict__ Q,
                                               const __bf16* __restrict__ K,
                                               const __bf16* __restrict__ Vt,
                                               const int* __restrict__ mask,
                                               __bf16* __restrict__ O) {
    // K ring: [0, 24576) = 3 x 8192 ; V ring: [24576, 57344) = 4 x 8192 ;
    // mask f32: [57344, 73728)
    __shared__ char smem[73728];

    int tid = threadIdx.x, lane = tid & 63, wid = tid >> 6;
    int c = lane & 15, g = lane >> 4;

    // XCD-chunked swizzle: 512 blocks, 64 per XCD -> each XCD sees 2 bh values.
    int sw = (blockIdx.x & 7) * 64 + (blockIdx.x >> 3);
    int bh = sw >> 5, b = bh >> 3, h = bh & 7;
    int q0 = (sw & 31) * 128;

    const __bf16* Qb = Q + (size_t)bh * 4096 * 64;
    const __bf16* Kb = K + (size_t)bh * 4096 * 64;
    const __bf16* Vb = Vt + (size_t)bh * 64 * 4096;
    int qw = q0 + wid * 32;

    // mask int -> additive float -> LDS (fused maskprep)
    {
        const int4* msrc = (const int4*)(mask + (size_t)b * 4096);
        float4* mdst = (float4*)(smem + 57344);
#pragma unroll
        for (int p = 0; p < 4; ++p) {
            int4 m = msrc[p * 256 + tid];
            float4 f = {m.x ? 0.f : -1e30f, m.y ? 0.f : -1e30f,
                        m.z ? 0.f : -1e30f, m.w ? 0.f : -1e30f};
            mdst[p * 256 + tid] = f;
        }
    }

    // Q fragments (B operand of S^T = K Q^T)
    bf16x8 qf[2][2];
#pragma unroll
    for (int nq = 0; nq < 2; ++nq)
#pragma unroll
        for (int ks = 0; ks < 2; ++ks)
            qf[nq][ks] = *(const bf16x8*)(Qb + (size_t)(qw + nq * 16 + c) * 64 +
                                          g * 8 + ks * 32);

    // staging bases (pre-swizzled global source, linear LDS dest)
    int rowp = tid >> 3;                               // 0..31
    int jlow = ((tid & 7) << 4) ^ ((rowp & 7) << 4);   // p-independent
    const char* kB0 = (const char*)Kb + rowp * 128 + jlow;
    const char* kB1 = (const char*)Kb + (32 + rowp) * 128 + jlow;
    const char* vB0 = (const char*)Vb + rowp * 8192 + jlow;
    const char* vB1 = (const char*)Vb + (32 + rowp) * 8192 + jlow;
    int woff = (tid >> 6) * 1024;

#define STAGE(t)                                                              \
    {                                                                         \
        int uk_ = (t) % 3, uv_ = (t) & 3;                                     \
        size_t ko_ = (size_t)(t) * 8192, vo_ = (size_t)(t) * 128;             \
        gload_lds16(smem + uk_ * 8192 + woff, kB0 + ko_);                     \
        gload_lds16(smem + uk_ * 8192 + 4096 + woff, kB1 + ko_);              \
        gload_lds16(smem + 24576 + uv_ * 8192 + woff, vB0 + vo_);             \
        gload_lds16(smem + 24576 + uv_ * 8192 + 4096 + woff, vB1 + vo_);      \
    }

    f32x4 zero = {0.f, 0.f, 0.f, 0.f};
    f32x4 acc[4][2];  // acc[hd-tile][q-tile]: row=hd, col=q
#pragma unroll
    for (int i = 0; i < 4; ++i)
#pragma unroll
        for (int j = 0; j < 2; ++j) acc[i][j] = zero;
    f32x4 rsum4[2] = {zero, zero};  // per-lane partial row sums

    // S^T(t) = mask + K(t) Q^T, into s (mask seeds the MFMA accumulator)
    auto QKT = [&](int t, f32x4(&s)[4][2]) {
        const char* Ktc = smem + (t % 3) * 8192;
#pragma unroll
        for (int mt = 0; mt < 4; ++mt) {
            f32x4 mv =
                *(const f32x4*)(smem + 57344 + t * 256 + mt * 64 + g * 16);
            s[mt][0] = mv;
            s[mt][1] = mv;
        }
        __builtin_amdgcn_s_setprio(1);
#pragma unroll
        for (int ks = 0; ks < 2; ++ks) {
            bf16x8 kf[4];
#pragma unroll
            for (int mt = 0; mt < 4; ++mt)
                kf[mt] = frag_ld(Ktc, mt * 16 + c, g * 16 + ks * 64);
#pragma unroll
            for (int mt = 0; mt < 4; ++mt)
#pragma unroll
                for (int nq = 0; nq < 2; ++nq)
                    s[mt][nq] = MFMA16(kf[mt], qf[nq][ks], s[mt][nq]);
        }
        __builtin_amdgcn_s_setprio(0);
    };

    // softmax(s) in-register + PV(t): x^T += V(t)^T P^T
    auto SMPV = [&](int t, f32x4(&s)[4][2]) {
        const char* Vtc = smem + 24576 + (t & 3) * 8192;
        unsigned int pku[4][2][2];
#pragma unroll
        for (int mt = 0; mt < 4; ++mt)
#pragma unroll
            for (int nq = 0; nq < 2; ++nq) {
                f32x4 p;
#pragma unroll
                for (int j = 0; j < 4; ++j)
                    p[j] = __builtin_amdgcn_exp2f(s[mt][nq][j]);
                rsum4[nq] += p;
                bf16x4 pw = {(__bf16)p[0], (__bf16)p[1], (__bf16)p[2],
                             (__bf16)p[3]};
                u32x2 u2 = __builtin_bit_cast(u32x2, pw);
                pku[mt][nq][0] = u2.x;
                pku[mt][nq][1] = u2.y;
            }
#pragma unroll
        for (int ks2 = 0; ks2 < 2; ++ks2) {
            bf16x8 vf[4];
#pragma unroll
            for (int mh = 0; mh < 4; ++mh)
                vf[mh] = frag_ld(Vtc, mh * 16 + c, g * 16 + ks2 * 64);
            bf16x8 pf[2];
#pragma unroll
            for (int nq = 0; nq < 2; ++nq) {
                unsigned int a0 = pku[2 * ks2][nq][0];
                unsigned int a1 = pku[2 * ks2][nq][1];
                unsigned int b0 = pku[2 * ks2 + 1][nq][0];
                unsigned int b1 = pku[2 * ks2 + 1][nq][1];
                asm("v_permlane32_swap_b32 %0, %1" : "+v"(a0), "+v"(b0));
                asm("v_permlane32_swap_b32 %0, %1" : "+v"(a1), "+v"(b1));
                asm("v_permlane16_swap_b32 %0, %1" : "+v"(a0), "+v"(b0));
                asm("v_permlane16_swap_b32 %0, %1" : "+v"(a1), "+v"(b1));
                u32x4 pv = {a0, a1, b0, b1};
                pf[nq] = __builtin_bit_cast(bf16x8, pv);
            }
            __builtin_amdgcn_s_setprio(1);
#pragma unroll
            for (int mh = 0; mh < 4; ++mh)
#pragma unroll
                for (int nq = 0; nq < 2; ++nq)
                    acc[mh][nq] = MFMA16(vf[mh], pf[nq], acc[mh][nq]);
            __builtin_amdgcn_s_setprio(0);
        }
    };

    // drain prologue vmem (mask/Q loads) + LDS mask writes, then prime pipeline
    asm volatile("s_waitcnt vmcnt(0) lgkmcnt(0)" ::: "memory");
    __builtin_amdgcn_sched_barrier(0);
    STAGE(0);
    STAGE(1);
    STAGE(2);
    asm volatile("s_waitcnt vmcnt(8)" ::: "memory");  // tile 0 landed
    __builtin_amdgcn_s_barrier();
    __builtin_amdgcn_sched_barrier(0);

    f32x4 sA[4][2], sB[4][2];
    QKT(0, sA);

#pragma unroll 1
    for (int tt = 0; tt < 32; ++tt) {
        int t0 = 2 * tt, t1 = 2 * tt + 1;
        // ---- iter t0: prev in sA, next into sB ----
        asm volatile("s_waitcnt vmcnt(0)" ::: "memory");
        __builtin_amdgcn_s_barrier();
        __builtin_amdgcn_sched_barrier(0);
        if (t0 <= 60) STAGE(t0 + 3);
        if (t0 < 63) QKT(t0 + 1, sB);
        SMPV(t0, sA);
        // ---- iter t1: prev in sB, next into sA ----
        asm volatile("s_waitcnt vmcnt(0)" ::: "memory");
        __builtin_amdgcn_s_barrier();
        __builtin_amdgcn_sched_barrier(0);
        if (t1 <= 60) STAGE(t1 + 3);
        if (t1 < 63) QKT(t1 + 1, sA);
        SMPV(t1, sB);
    }
#undef STAGE

    // final L reduce: horizontal sum + 2 shfl over g-groups
    float rl[2];
#pragma unroll
    for (int nq = 0; nq < 2; ++nq) {
        float r = (rsum4[nq][0] + rsum4[nq][1]) + (rsum4[nq][2] + rsum4[nq][3]);
        r += __shfl_xor(r, 16, 64);
        r += __shfl_xor(r, 32, 64);
        rl[nq] = 1.0f / r;
    }

    __syncthreads();  // full drain before reusing LDS for O staging

    // normalize, stage O tile [128 q][64 hd] in smem (pitch 144), coalesced store
    char* Pw = smem + wid * 4608;
#pragma unroll
    for (int mh = 0; mh < 4; ++mh)
#pragma unroll
        for (int nq = 0; nq < 2; ++nq) {
            bf16x4 o;
#pragma unroll
            for (int j = 0; j < 4; ++j) o[j] = (__bf16)(acc[mh][nq][j] * rl[nq]);
            *(bf16x4*)(Pw + (nq * 16 + c) * 144 + mh * 32 + g * 8) = o;
        }
    __syncthreads();
#pragma unroll
    for (int p = 0; p < 4; ++p) {
        int i = p * 4096 + tid * 16;
        int row = i >> 7, colb = i & 127;
        bf16x8 v = *(const bf16x8*)(smem + row * 144 + colb);
        *(bf16x8*)(O + ((size_t)(b * 4096 + q0 + row)) * 512 + h * 64 +
                   colb / 2) = v;
    }
}

extern "C" void kernel_launch(void* const* d_in, const int* in_sizes, int n_in,
                              void* d_out, int out_size, void* d_ws,
                              size_t ws_size, hipStream_t stream) {
    const float* query = (const float*)d_in[0];
    const float* key = (const float*)d_in[1];
    const float* value = (const float*)d_in[2];
    const int* mask = (const int*)d_in[3];
    const float* Wq = (const float*)d_in[4];
    const float* bq = (const float*)d_in[5];
    const float* Wk = (const float*)d_in[6];
    const float* bk = (const float*)d_in[7];
    const float* Wv = (const float*)d_in[8];
    const float* bv = (const float*)d_in[9];
    const float* Wo = (const float*)d_in[10];
    const float* bo = (const float*)d_in[11];

    char* ws = (char*)d_ws;
    __bf16* Xbf = (__bf16*)(ws);                  // 25165824 B
    __bf16* Wt = (__bf16*)(ws + 25165824);        // 2097152 B
    __bf16* Qb = (__bf16*)(ws + 27262976);        // 8388608 B
    __bf16* Kb = (__bf16*)(ws + 35651584);        // 8388608 B
    __bf16* Vtb = (__bf16*)(ws + 44040192);       // 8388608 B
    __bf16* Ob = (__bf16*)(ws + 52428800);        // 8388608 B

    cast_x<<<dim3(4096, 1, 3), 256, 0, stream>>>(query, key, value, Xbf);
    wtrans<<<dim3(16, 16, 4), 256, 0, stream>>>(Wq, Wk, Wv, Wo, Wt);
    gemm_qkv<<<dim3(64, 4, 3), 256, 0, stream>>>(Xbf, Wt, bq, bk, bv, Qb, Kb,
                                                 Vtb, 0, nullptr);
    attn_fa<<<dim3(512), 256, 0, stream>>>(Qb, Kb, Vtb, mask, Ob);
    gemm_qkv<<<dim3(64, 4, 1), 256, 0, stream>>>(Ob, Wt + 3 * 262144, bo, bo,
                                                 bo, Qb, Kb, Vtb, 3,
                                                 (float*)d_out);
}

// Round 15
// 135.163 us; speedup vs baseline: 1.4549x; 1.0444x over previous
//
#include <hip/hip_runtime.h>
#include <cmath>

typedef __attribute__((ext_vector_type(8))) __bf16 bf16x8;
typedef __attribute__((ext_vector_type(4))) __bf16 bf16x4;
typedef __attribute__((ext_vector_type(4))) float f32x4;
typedef __attribute__((ext_vector_type(2))) unsigned int u32x2;
typedef __attribute__((ext_vector_type(4))) unsigned int u32x4;

#define MFMA16(a, b, c) __builtin_amdgcn_mfma_f32_16x16x32_bf16(a, b, c, 0, 0, 0)

// 0.125 (1/sqrt(HD)) * log2(e): folded into Q projection so softmax can use exp2.
#define QSCALE 0.1803368801111601f

__device__ __forceinline__ void gload_lds16(void* lds, const void* g) {
    __builtin_amdgcn_global_load_lds(
        (const __attribute__((address_space(1))) unsigned int*)g,
        (__attribute__((address_space(3))) unsigned int*)lds, 16, 0, 0);
}

// Stage PASSES*4096 bytes of a [rows][64 bf16] tile (row = 128B) into LDS,
// XOR-swizzled: LDS linear byte i holds tile byte i ^ ((row&7)<<4).
template <int PASSES>
__device__ __forceinline__ void stage_tile(char* lds, const __bf16* src,
                                           int stride_elems, int tid) {
    const char* s = (const char*)src;
    char* wbase = lds + (tid >> 6) * 1024;
#pragma unroll
    for (int p = 0; p < PASSES; ++p) {
        int i = p * 4096 + tid * 16;
        int row = i >> 7;
        int j = i ^ ((row & 7) << 4);
        gload_lds16(wbase + p * 4096,
                    s + (size_t)row * stride_elems * 2 + (j & 127));
    }
}

// Stage PASSES*4096 bytes of a [rows][64 f32] tile (row = 256B) into LDS,
// XOR-swizzled on bits 5..7: byte i holds tile byte i ^ ((row&7)<<5).
template <int PASSES>
__device__ __forceinline__ void stage_tile_f32(char* lds, const float* src,
                                               int stride_elems, int tid) {
    const char* s = (const char*)src;
    char* wbase = lds + (tid >> 6) * 1024;
#pragma unroll
    for (int p = 0; p < PASSES; ++p) {
        int i = p * 4096 + tid * 16;
        int row = i >> 8;
        int j = i ^ ((row & 7) << 5);
        gload_lds16(wbase + p * 4096,
                    s + (size_t)row * stride_elems * 4 + (j & 255));
    }
}

// Read one bf16x8 MFMA fragment from a swizzled [rows][64 bf16] tile.
__device__ __forceinline__ bf16x8 frag_ld(const char* tile, int row, int kb) {
    int addr = (row << 7) + kb;
    addr ^= ((row & 7) << 4);
    return *(const bf16x8*)(tile + addr);
}

// Read one bf16x8 fragment from a swizzled [rows][64 f32] tile (converting).
// kb is the byte offset of the 8-f32 group within the 256B row (32B-aligned,
// so both 16B halves stay inside one 32B swizzle granule).
__device__ __forceinline__ bf16x8 frag_ld_f32(const char* tile, int row,
                                              int kb) {
    int addr = (row << 8) + kb;
    addr ^= ((row & 7) << 5);
    f32x4 lo = *(const f32x4*)(tile + addr);
    f32x4 hi = *(const f32x4*)(tile + addr + 16);
    bf16x8 r = {(__bf16)lo[0], (__bf16)lo[1], (__bf16)lo[2], (__bf16)lo[3],
                (__bf16)hi[0], (__bf16)hi[1], (__bf16)hi[2], (__bf16)hi[3]};
    return r;
}

// ---------------- transpose weights fp32[512][512] -> bf16 Wt[n][k] ----------------
__global__ __launch_bounds__(256) void wtrans(const float* __restrict__ Wq,
                                              const float* __restrict__ Wk,
                                              const float* __restrict__ Wv,
                                              const float* __restrict__ Wo,
                                              __bf16* __restrict__ Wt) {
    int z = blockIdx.z;
    const float* W = (z == 0) ? Wq : (z == 1) ? Wk : (z == 2) ? Wv : Wo;
    __bf16* out = Wt + (size_t)z * 262144;
    __shared__ float t[32][33];
    int r = threadIdx.x >> 5, cc = threadIdx.x & 31;
    int k0 = blockIdx.y * 32, n0 = blockIdx.x * 32;
#pragma unroll
    for (int rr = 0; rr < 4; ++rr)
        t[r + rr * 8][cc] = W[(size_t)(k0 + r + rr * 8) * 512 + n0 + cc];
    __syncthreads();
#pragma unroll
    for (int rr = 0; rr < 4; ++rr)
        out[(size_t)(n0 + r + rr * 8) * 512 + k0 + cc] = (__bf16)t[cc][r + rr * 8];
}

// ---------------- 128x128 tiled bf16 GEMM: out = A(8192x512) * W + bias ------
// AF32=true: A operand read directly from fp32 (QKV projections; fuses the
// former cast_x kernel into the GEMM staging — bit-identical numerics).
// mode 0: -> Q [B,H,L,64] (scaled)  mode 1: -> K  mode 2: -> Vt [B,H,64,L]
// mode 3 (AF32=false): -> fp32 d_out.
template <bool AF32>
__global__ __launch_bounds__(256) void gemm_qkv(
    const float* __restrict__ Af0, const float* __restrict__ Af1,
    const float* __restrict__ Af2, const __bf16* __restrict__ Ab,
    const __bf16* __restrict__ Wt, const float* __restrict__ b0,
    const float* __restrict__ b1, const float* __restrict__ b2,
    __bf16* __restrict__ Qo, __bf16* __restrict__ Ko,
    __bf16* __restrict__ Vto, int modeBase, float* __restrict__ outF) {
    __shared__ char smem[49152];
    char* At = smem;           // AF32: 32KB (f32), else 16KB (bf16)
    char* Bt = smem + 32768;   // 16KB bf16
    int z = blockIdx.z;
    int mode = modeBase + z;
    const float* Af = (z == 0) ? Af0 : (z == 1) ? Af1 : Af2;
    const __bf16* B = Wt + (size_t)z * 262144;
    const float* bias = (mode == 1) ? b1 : (mode == 2) ? b2 : b0;

    int tid = threadIdx.x;
    int lane = tid & 63, wid = tid >> 6;
    int c = lane & 15, g = lane >> 4;
    int wm = (wid >> 1) * 64, wn = (wid & 1) * 64;
    int m0 = blockIdx.x * 128, n0 = blockIdx.y * 128;

    f32x4 zero = {0.f, 0.f, 0.f, 0.f};
    f32x4 acc[4][4];
#pragma unroll
    for (int i = 0; i < 4; ++i)
#pragma unroll
        for (int j = 0; j < 4; ++j) acc[i][j] = zero;

    for (int k0 = 0; k0 < 512; k0 += 64) {
        __syncthreads();
        if constexpr (AF32)
            stage_tile_f32<8>(At, Af + (size_t)m0 * 512 + k0, 512, tid);
        else
            stage_tile<4>(At, Ab + (size_t)m0 * 512 + k0, 512, tid);
        stage_tile<4>(Bt, B + (size_t)n0 * 512 + k0, 512, tid);
        __syncthreads();
#pragma unroll
        for (int ks = 0; ks < 2; ++ks) {
            bf16x8 af[4], bff[4];
#pragma unroll
            for (int mt = 0; mt < 4; ++mt) {
                if constexpr (AF32)
                    af[mt] = frag_ld_f32(At, wm + mt * 16 + c,
                                         g * 32 + ks * 128);
                else
                    af[mt] = frag_ld(At, wm + mt * 16 + c, g * 16 + ks * 64);
            }
#pragma unroll
            for (int nt = 0; nt < 4; ++nt)
                bff[nt] = frag_ld(Bt, wn + nt * 16 + c, g * 16 + ks * 64);
#pragma unroll
            for (int mt = 0; mt < 4; ++mt)
#pragma unroll
                for (int nt = 0; nt < 4; ++nt)
                    acc[mt][nt] = MFMA16(af[mt], bff[nt], acc[mt][nt]);
        }
    }

    float bv[4];
#pragma unroll
    for (int nt = 0; nt < 4; ++nt) bv[nt] = bias[n0 + wn + nt * 16 + c];
    float sc = (mode == 0) ? QSCALE : 1.0f;

    if (mode == 3) {
#pragma unroll
        for (int mt = 0; mt < 4; ++mt)
#pragma unroll
            for (int nt = 0; nt < 4; ++nt)
#pragma unroll
                for (int j = 0; j < 4; ++j) {
                    int m = m0 + wm + mt * 16 + g * 4 + j;
                    int n = n0 + wn + nt * 16 + c;
                    outF[(size_t)m * 512 + n] = acc[mt][nt][j] + bv[nt];
                }
    } else if (mode == 2) {
#pragma unroll
        for (int mt = 0; mt < 4; ++mt)
#pragma unroll
            for (int nt = 0; nt < 4; ++nt) {
                int m = m0 + wm + mt * 16 + g * 4;
                int n = n0 + wn + nt * 16 + c;
                int b = m >> 12, l = m & 4095, hh = n >> 6, hd = n & 63;
                bf16x4 v;
#pragma unroll
                for (int j = 0; j < 4; ++j)
                    v[j] = (__bf16)(acc[mt][nt][j] + bv[nt]);
                *(bf16x4*)(Vto + ((size_t)((b * 8 + hh) * 64 + hd)) * 4096 + l) = v;
            }
    } else {
        __bf16* dst = (mode == 0) ? Qo : Ko;
#pragma unroll
        for (int mt = 0; mt < 4; ++mt)
#pragma unroll
            for (int nt = 0; nt < 4; ++nt)
#pragma unroll
                for (int j = 0; j < 4; ++j) {
                    int m = m0 + wm + mt * 16 + g * 4 + j;
                    int n = n0 + wn + nt * 16 + c;
                    int b = m >> 12, l = m & 4095, hh = n >> 6, hd = n & 63;
                    dst[((size_t)((b * 8 + hh) * 4096 + l)) * 64 + hd] =
                        (__bf16)((acc[mt][nt][j] + bv[nt]) * sc);
                }
    }
}

// ---------------- flash attention (byte-identical to R14/R7 verified) -----
// Swapped QK^T (softmax per-lane), static max, P in registers (permlane),
// software-pipelined: QK^T(t+1) issued alongside softmax(t)+PV(t). K ring
// 3-deep, V ring 4-deep; STAGE(t+3) after the barrier; vmcnt(0)+barrier at
// iter top.
__global__ __launch_bounds__(256) void attn_fa(const __bf16* __restrict__ Q,
                                               const __bf16* __restrict__ K,
                                               const __bf16* __restrict__ Vt,
                                               const int* __restrict__ mask,
                                               __bf16* __restrict__ O) {
    // K ring: [0, 24576) = 3 x 8192 ; V ring: [24576, 57344) = 4 x 8192 ;
    // mask f32: [57344, 73728)
    __shared__ char smem[73728];

    int tid = threadIdx.x, lane = tid & 63, wid = tid >> 6;
    int c = lane & 15, g = lane >> 4;

    // XCD-chunked swizzle: 512 blocks, 64 per XCD -> each XCD sees 2 bh values.
    int sw = (blockIdx.x & 7) * 64 + (blockIdx.x >> 3);
    int bh = sw >> 5, b = bh >> 3, h = bh & 7;
    int q0 = (sw & 31) * 128;

    const __bf16* Qb = Q + (size_t)bh * 4096 * 64;
    const __bf16* Kb = K + (size_t)bh * 4096 * 64;
    const __bf16* Vb = Vt + (size_t)bh * 64 * 4096;
    int qw = q0 + wid * 32;

    // mask int -> additive float -> LDS (fused maskprep)
    {
        const int4* msrc = (const int4*)(mask + (size_t)b * 4096);
        float4* mdst = (float4*)(smem + 57344);
#pragma unroll
        for (int p = 0; p < 4; ++p) {
            int4 m = msrc[p * 256 + tid];
            float4 f = {m.x ? 0.f : -1e30f, m.y ? 0.f : -1e30f,
                        m.z ? 0.f : -1e30f, m.w ? 0.f : -1e30f};
            mdst[p * 256 + tid] = f;
        }
    }

    // Q fragments (B operand of S^T = K Q^T)
    bf16x8 qf[2][2];
#pragma unroll
    for (int nq = 0; nq < 2; ++nq)
#pragma unroll
        for (int ks = 0; ks < 2; ++ks)
            qf[nq][ks] = *(const bf16x8*)(Qb + (size_t)(qw + nq * 16 + c) * 64 +
                                          g * 8 + ks * 32);

    // staging bases (pre-swizzled global source, linear LDS dest)
    int rowp = tid >> 3;                               // 0..31
    int jlow = ((tid & 7) << 4) ^ ((rowp & 7) << 4);   // p-independent
    const char* kB0 = (const char*)Kb + rowp * 128 + jlow;
    const char* kB1 = (const char*)Kb + (32 + rowp) * 128 + jlow;
    const char* vB0 = (const char*)Vb + rowp * 8192 + jlow;
    const char* vB1 = (const char*)Vb + (32 + rowp) * 8192 + jlow;
    int woff = (tid >> 6) * 1024;

#define STAGE(t)                                                              \
    {                                                                         \
        int uk_ = (t) % 3, uv_ = (t) & 3;                                     \
        size_t ko_ = (size_t)(t) * 8192, vo_ = (size_t)(t) * 128;             \
        gload_lds16(smem + uk_ * 8192 + woff, kB0 + ko_);                     \
        gload_lds16(smem + uk_ * 8192 + 4096 + woff, kB1 + ko_);              \
        gload_lds16(smem + 24576 + uv_ * 8192 + woff, vB0 + vo_);             \
        gload_lds16(smem + 24576 + uv_ * 8192 + 4096 + woff, vB1 + vo_);      \
    }

    f32x4 zero = {0.f, 0.f, 0.f, 0.f};
    f32x4 acc[4][2];  // acc[hd-tile][q-tile]: row=hd, col=q
#pragma unroll
    for (int i = 0; i < 4; ++i)
#pragma unroll
        for (int j = 0; j < 2; ++j) acc[i][j] = zero;
    f32x4 rsum4[2] = {zero, zero};  // per-lane partial row sums

    // S^T(t) = mask + K(t) Q^T, into s (mask seeds the MFMA accumulator)
    auto QKT = [&](int t, f32x4(&s)[4][2]) {
        const char* Ktc = smem + (t % 3) * 8192;
#pragma unroll
        for (int mt = 0; mt < 4; ++mt) {
            f32x4 mv =
                *(const f32x4*)(smem + 57344 + t * 256 + mt * 64 + g * 16);
            s[mt][0] = mv;
            s[mt][1] = mv;
        }
        __builtin_amdgcn_s_setprio(1);
#pragma unroll
        for (int ks = 0; ks < 2; ++ks) {
            bf16x8 kf[4];
#pragma unroll
            for (int mt = 0; mt < 4; ++mt)
                kf[mt] = frag_ld(Ktc, mt * 16 + c, g * 16 + ks * 64);
#pragma unroll
            for (int mt = 0; mt < 4; ++mt)
#pragma unroll
                for (int nq = 0; nq < 2; ++nq)
                    s[mt][nq] = MFMA16(kf[mt], qf[nq][ks], s[mt][nq]);
        }
        __builtin_amdgcn_s_setprio(0);
    };

    // softmax(s) in-register + PV(t): x^T += V(t)^T P^T
    auto SMPV = [&](int t, f32x4(&s)[4][2]) {
        const char* Vtc = smem + 24576 + (t & 3) * 8192;
        unsigned int pku[4][2][2];
#pragma unroll
        for (int mt = 0; mt < 4; ++mt)
#pragma unroll
            for (int nq = 0; nq < 2; ++nq) {
                f32x4 p;
#pragma unroll
                for (int j = 0; j < 4; ++j)
                    p[j] = __builtin_amdgcn_exp2f(s[mt][nq][j]);
                rsum4[nq] += p;
                bf16x4 pw = {(__bf16)p[0], (__bf16)p[1], (__bf16)p[2],
                             (__bf16)p[3]};
                u32x2 u2 = __builtin_bit_cast(u32x2, pw);
                pku[mt][nq][0] = u2.x;
                pku[mt][nq][1] = u2.y;
            }
#pragma unroll
        for (int ks2 = 0; ks2 < 2; ++ks2) {
            bf16x8 vf[4];
#pragma unroll
            for (int mh = 0; mh < 4; ++mh)
                vf[mh] = frag_ld(Vtc, mh * 16 + c, g * 16 + ks2 * 64);
            bf16x8 pf[2];
#pragma unroll
            for (int nq = 0; nq < 2; ++nq) {
                unsigned int a0 = pku[2 * ks2][nq][0];
                unsigned int a1 = pku[2 * ks2][nq][1];
                unsigned int b0 = pku[2 * ks2 + 1][nq][0];
                unsigned int b1 = pku[2 * ks2 + 1][nq][1];
                asm("v_permlane32_swap_b32 %0, %1" : "+v"(a0), "+v"(b0));
                asm("v_permlane32_swap_b32 %0, %1" : "+v"(a1), "+v"(b1));
                asm("v_permlane16_swap_b32 %0, %1" : "+v"(a0), "+v"(b0));
                asm("v_permlane16_swap_b32 %0, %1" : "+v"(a1), "+v"(b1));
                u32x4 pv = {a0, a1, b0, b1};
                pf[nq] = __builtin_bit_cast(bf16x8, pv);
            }
            __builtin_amdgcn_s_setprio(1);
#pragma unroll
            for (int mh = 0; mh < 4; ++mh)
#pragma unroll
                for (int nq = 0; nq < 2; ++nq)
                    acc[mh][nq] = MFMA16(vf[mh], pf[nq], acc[mh][nq]);
            __builtin_amdgcn_s_setprio(0);
        }
    };

    // drain prologue vmem (mask/Q loads) + LDS mask writes, then prime pipeline
    asm volatile("s_waitcnt vmcnt(0) lgkmcnt(0)" ::: "memory");
    __builtin_amdgcn_sched_barrier(0);
    STAGE(0);
    STAGE(1);
    STAGE(2);
    asm volatile("s_waitcnt vmcnt(8)" ::: "memory");  // tile 0 landed
    __builtin_amdgcn_s_barrier();
    __builtin_amdgcn_sched_barrier(0);

    f32x4 sA[4][2], sB[4][2];
    QKT(0, sA);

#pragma unroll 1
    for (int tt = 0; tt < 32; ++tt) {
        int t0 = 2 * tt, t1 = 2 * tt + 1;
        // ---- iter t0: prev in sA, next into sB ----
        asm volatile("s_waitcnt vmcnt(0)" ::: "memory");
        __builtin_amdgcn_s_barrier();
        __builtin_amdgcn_sched_barrier(0);
        if (t0 <= 60) STAGE(t0 + 3);
        if (t0 < 63) QKT(t0 + 1, sB);
        SMPV(t0, sA);
        // ---- iter t1: prev in sB, next into sA ----
        asm volatile("s_waitcnt vmcnt(0)" ::: "memory");
        __builtin_amdgcn_s_barrier();
        __builtin_amdgcn_sched_barrier(0);
        if (t1 <= 60) STAGE(t1 + 3);
        if (t1 < 63) QKT(t1 + 1, sA);
        SMPV(t1, sB);
    }
#undef STAGE

    // final L reduce: horizontal sum + 2 shfl over g-groups
    float rl[2];
#pragma unroll
    for (int nq = 0; nq < 2; ++nq) {
        float r = (rsum4[nq][0] + rsum4[nq][1]) + (rsum4[nq][2] + rsum4[nq][3]);
        r += __shfl_xor(r, 16, 64);
        r += __shfl_xor(r, 32, 64);
        rl[nq] = 1.0f / r;
    }

    __syncthreads();  // full drain before reusing LDS for O staging

    // normalize, stage O tile [128 q][64 hd] in smem (pitch 144), coalesced store
    char* Pw = smem + wid * 4608;
#pragma unroll
    for (int mh = 0; mh < 4; ++mh)
#pragma unroll
        for (int nq = 0; nq < 2; ++nq) {
            bf16x4 o;
#pragma unroll
            for (int j = 0; j < 4; ++j) o[j] = (__bf16)(acc[mh][nq][j] * rl[nq]);
            *(bf16x4*)(Pw + (nq * 16 + c) * 144 + mh * 32 + g * 8) = o;
        }
    __syncthreads();
#pragma unroll
    for (int p = 0; p < 4; ++p) {
        int i = p * 4096 + tid * 16;
        int row = i >> 7, colb = i & 127;
        bf16x8 v = *(const bf16x8*)(smem + row * 144 + colb);
        *(bf16x8*)(O + ((size_t)(b * 4096 + q0 + row)) * 512 + h * 64 +
                   colb / 2) = v;
    }
}

extern "C" void kernel_launch(void* const* d_in, const int* in_sizes, int n_in,
                              void* d_out, int out_size, void* d_ws,
                              size_t ws_size, hipStream_t stream) {
    const float* query = (const float*)d_in[0];
    const float* key = (const float*)d_in[1];
    const float* value = (const float*)d_in[2];
    const int* mask = (const int*)d_in[3];
    const float* Wq = (const float*)d_in[4];
    const float* bq = (const float*)d_in[5];
    const float* Wk = (const float*)d_in[6];
    const float* bk = (const float*)d_in[7];
    const float* Wv = (const float*)d_in[8];
    const float* bv = (const float*)d_in[9];
    const float* Wo = (const float*)d_in[10];
    const float* bo = (const float*)d_in[11];

    char* ws = (char*)d_ws;
    __bf16* Wt = (__bf16*)(ws + 25165824);        // 2097152 B
    __bf16* Qb = (__bf16*)(ws + 27262976);        // 8388608 B
    __bf16* Kb = (__bf16*)(ws + 35651584);        // 8388608 B
    __bf16* Vtb = (__bf16*)(ws + 44040192);       // 8388608 B
    __bf16* Ob = (__bf16*)(ws + 52428800);        // 8388608 B

    wtrans<<<dim3(16, 16, 4), 256, 0, stream>>>(Wq, Wk, Wv, Wo, Wt);
    gemm_qkv<true><<<dim3(64, 4, 3), 256, 0, stream>>>(
        query, key, value, nullptr, Wt, bq, bk, bv, Qb, Kb, Vtb, 0, nullptr);
    attn_fa<<<dim3(512), 256, 0, stream>>>(Qb, Kb, Vtb, mask, Ob);
    gemm_qkv<false><<<dim3(64, 4, 1), 256, 0, stream>>>(
        nullptr, nullptr, nullptr, Ob, Wt + 3 * 262144, bo, bo, bo, Qb, Kb,
        Vtb, 3, (float*)d_out);
}

// Round 17
// 134.980 us; speedup vs baseline: 1.4568x; 1.0014x over previous
//
#include <hip/hip_runtime.h>
#include <cmath>

typedef __attribute__((ext_vector_type(8))) __bf16 bf16x8;
typedef __attribute__((ext_vector_type(4))) __bf16 bf16x4;
typedef __attribute__((ext_vector_type(4))) float f32x4;
typedef __attribute__((ext_vector_type(2))) unsigned int u32x2;
typedef __attribute__((ext_vector_type(4))) unsigned int u32x4;

#define MFMA16(a, b, c) __builtin_amdgcn_mfma_f32_16x16x32_bf16(a, b, c, 0, 0, 0)

// 0.125 (1/sqrt(HD)) * log2(e): folded into Q projection so softmax can use exp2.
#define QSCALE 0.1803368801111601f

__device__ __forceinline__ void gload_lds16(void* lds, const void* g) {
    __builtin_amdgcn_global_load_lds(
        (const __attribute__((address_space(1))) unsigned int*)g,
        (__attribute__((address_space(3))) unsigned int*)lds, 16, 0, 0);
}

// Stage PASSES*4096 bytes of a [rows][64 bf16] tile (row = 128B) into LDS,
// XOR-swizzled: LDS linear byte i holds tile byte i ^ ((row&7)<<4).
template <int PASSES>
__device__ __forceinline__ void stage_tile(char* lds, const __bf16* src,
                                           int stride_elems, int tid) {
    const char* s = (const char*)src;
    char* wbase = lds + (tid >> 6) * 1024;
#pragma unroll
    for (int p = 0; p < PASSES; ++p) {
        int i = p * 4096 + tid * 16;
        int row = i >> 7;
        int j = i ^ ((row & 7) << 4);
        gload_lds16(wbase + p * 4096,
                    s + (size_t)row * stride_elems * 2 + (j & 127));
    }
}

// Stage PASSES*4096 bytes of a [rows][64 f32] tile (row = 256B) into LDS,
// XOR-swizzled on bits 5..7: byte i holds tile byte i ^ ((row&7)<<5).
template <int PASSES>
__device__ __forceinline__ void stage_tile_f32(char* lds, const float* src,
                                               int stride_elems, int tid) {
    const char* s = (const char*)src;
    char* wbase = lds + (tid >> 6) * 1024;
#pragma unroll
    for (int p = 0; p < PASSES; ++p) {
        int i = p * 4096 + tid * 16;
        int row = i >> 8;
        int j = i ^ ((row & 7) << 5);
        gload_lds16(wbase + p * 4096,
                    s + (size_t)row * stride_elems * 4 + (j & 255));
    }
}

// Read one bf16x8 MFMA fragment from a swizzled [rows][64 bf16] tile.
__device__ __forceinline__ bf16x8 frag_ld(const char* tile, int row, int kb) {
    int addr = (row << 7) + kb;
    addr ^= ((row & 7) << 4);
    return *(const bf16x8*)(tile + addr);
}

// Read one bf16x8 fragment from a swizzled [rows][64 f32] tile (converting).
// kb is the byte offset of the 8-f32 group within the 256B row (32B-aligned,
// so both 16B halves stay inside one 32B swizzle granule).
__device__ __forceinline__ bf16x8 frag_ld_f32(const char* tile, int row,
                                              int kb) {
    int addr = (row << 8) + kb;
    addr ^= ((row & 7) << 5);
    f32x4 lo = *(const f32x4*)(tile + addr);
    f32x4 hi = *(const f32x4*)(tile + addr + 16);
    bf16x8 r = {(__bf16)lo[0], (__bf16)lo[1], (__bf16)lo[2], (__bf16)lo[3],
                (__bf16)hi[0], (__bf16)hi[1], (__bf16)hi[2], (__bf16)hi[3]};
    return r;
}

// ---------------- transpose weights fp32[512][512] -> bf16 Wt[n][k] ----------------
__global__ __launch_bounds__(256) void wtrans(const float* __restrict__ Wq,
                                              const float* __restrict__ Wk,
                                              const float* __restrict__ Wv,
                                              const float* __restrict__ Wo,
                                              __bf16* __restrict__ Wt) {
    int z = blockIdx.z;
    const float* W = (z == 0) ? Wq : (z == 1) ? Wk : (z == 2) ? Wv : Wo;
    __bf16* out = Wt + (size_t)z * 262144;
    __shared__ float t[32][33];
    int r = threadIdx.x >> 5, cc = threadIdx.x & 31;
    int k0 = blockIdx.y * 32, n0 = blockIdx.x * 32;
#pragma unroll
    for (int rr = 0; rr < 4; ++rr)
        t[r + rr * 8][cc] = W[(size_t)(k0 + r + rr * 8) * 512 + n0 + cc];
    __syncthreads();
#pragma unroll
    for (int rr = 0; rr < 4; ++rr)
        out[(size_t)(n0 + r + rr * 8) * 512 + k0 + cc] = (__bf16)t[cc][r + rr * 8];
}

// ---------------- 128x128 tiled bf16 GEMM: out = A(8192x512) * W + bias ------
// AF32=true: A operand read directly from fp32 (QKV projections; fuses the
// former cast_x kernel into the GEMM staging — bit-identical numerics).
// mode 0: -> Q [B,H,L,64] (scaled)  mode 1: -> K  mode 2: -> Vt [B,H,64,L]
// mode 3 (AF32=false): -> fp32 d_out.
template <bool AF32>
__global__ __launch_bounds__(256) void gemm_qkv(
    const float* __restrict__ Af0, const float* __restrict__ Af1,
    const float* __restrict__ Af2, const __bf16* __restrict__ Ab,
    const __bf16* __restrict__ Wt, const float* __restrict__ b0,
    const float* __restrict__ b1, const float* __restrict__ b2,
    __bf16* __restrict__ Qo, __bf16* __restrict__ Ko,
    __bf16* __restrict__ Vto, int modeBase, float* __restrict__ outF) {
    __shared__ char smem[49152];
    char* At = smem;           // AF32: 32KB (f32), else 16KB (bf16)
    char* Bt = smem + 32768;   // 16KB bf16
    int z = blockIdx.z;
    int mode = modeBase + z;
    const float* Af = (z == 0) ? Af0 : (z == 1) ? Af1 : Af2;
    const __bf16* B = Wt + (size_t)z * 262144;
    const float* bias = (mode == 1) ? b1 : (mode == 2) ? b2 : b0;

    int tid = threadIdx.x;
    int lane = tid & 63, wid = tid >> 6;
    int c = lane & 15, g = lane >> 4;
    int wm = (wid >> 1) * 64, wn = (wid & 1) * 64;
    int m0 = blockIdx.x * 128, n0 = blockIdx.y * 128;

    f32x4 zero = {0.f, 0.f, 0.f, 0.f};
    f32x4 acc[4][4];
#pragma unroll
    for (int i = 0; i < 4; ++i)
#pragma unroll
        for (int j = 0; j < 4; ++j) acc[i][j] = zero;

    for (int k0 = 0; k0 < 512; k0 += 64) {
        __syncthreads();
        if constexpr (AF32)
            stage_tile_f32<8>(At, Af + (size_t)m0 * 512 + k0, 512, tid);
        else
            stage_tile<4>(At, Ab + (size_t)m0 * 512 + k0, 512, tid);
        stage_tile<4>(Bt, B + (size_t)n0 * 512 + k0, 512, tid);
        __syncthreads();
#pragma unroll
        for (int ks = 0; ks < 2; ++ks) {
            bf16x8 af[4], bff[4];
#pragma unroll
            for (int mt = 0; mt < 4; ++mt) {
                if constexpr (AF32)
                    af[mt] = frag_ld_f32(At, wm + mt * 16 + c,
                                         g * 32 + ks * 128);
                else
                    af[mt] = frag_ld(At, wm + mt * 16 + c, g * 16 + ks * 64);
            }
#pragma unroll
            for (int nt = 0; nt < 4; ++nt)
                bff[nt] = frag_ld(Bt, wn + nt * 16 + c, g * 16 + ks * 64);
#pragma unroll
            for (int mt = 0; mt < 4; ++mt)
#pragma unroll
                for (int nt = 0; nt < 4; ++nt)
                    acc[mt][nt] = MFMA16(af[mt], bff[nt], acc[mt][nt]);
        }
    }

    float bv[4];
#pragma unroll
    for (int nt = 0; nt < 4; ++nt) bv[nt] = bias[n0 + wn + nt * 16 + c];
    float sc = (mode == 0) ? QSCALE : 1.0f;

    if (mode == 3) {
#pragma unroll
        for (int mt = 0; mt < 4; ++mt)
#pragma unroll
            for (int nt = 0; nt < 4; ++nt)
#pragma unroll
                for (int j = 0; j < 4; ++j) {
                    int m = m0 + wm + mt * 16 + g * 4 + j;
                    int n = n0 + wn + nt * 16 + c;
                    outF[(size_t)m * 512 + n] = acc[mt][nt][j] + bv[nt];
                }
    } else if (mode == 2) {
#pragma unroll
        for (int mt = 0; mt < 4; ++mt)
#pragma unroll
            for (int nt = 0; nt < 4; ++nt) {
                int m = m0 + wm + mt * 16 + g * 4;
                int n = n0 + wn + nt * 16 + c;
                int b = m >> 12, l = m & 4095, hh = n >> 6, hd = n & 63;
                bf16x4 v;
#pragma unroll
                for (int j = 0; j < 4; ++j)
                    v[j] = (__bf16)(acc[mt][nt][j] + bv[nt]);
                *(bf16x4*)(Vto + ((size_t)((b * 8 + hh) * 64 + hd)) * 4096 + l) = v;
            }
    } else {
        __bf16* dst = (mode == 0) ? Qo : Ko;
#pragma unroll
        for (int mt = 0; mt < 4; ++mt)
#pragma unroll
            for (int nt = 0; nt < 4; ++nt)
#pragma unroll
                for (int j = 0; j < 4; ++j) {
                    int m = m0 + wm + mt * 16 + g * 4 + j;
                    int n = n0 + wn + nt * 16 + c;
                    int b = m >> 12, l = m & 4095, hh = n >> 6, hd = n & 63;
                    dst[((size_t)((b * 8 + hh) * 4096 + l)) * 64 + hd] =
                        (__bf16)((acc[mt][nt][j] + bv[nt]) * sc);
                }
    }
}

// ---------------- flash attention (verified R7/R14/R15 kernel) -------------
// Swapped QK^T (softmax per-lane), static max, P in registers (permlane),
// software-pipelined: QK^T(t+1) issued alongside softmax(t)+PV(t). K ring
// 3-deep, V ring 4-deep; STAGE(t+3) after the barrier; vmcnt(0)+barrier at
// iter top.
__global__ __launch_bounds__(256) void attn_fa(const __bf16* __restrict__ Q,
                                               const __bf16* __restrict__ K,
                                               const __bf16* __restrict__ Vt,
                                               const int* __restrict__ mask,
                                               __bf16* __restrict__ O) {
    // K ring: [0, 24576) = 3 x 8192 ; V ring: [24576, 57344) = 4 x 8192 ;
    // mask f32: [57344, 73728)
    __shared__ char smem[73728];

    int tid = threadIdx.x, lane = tid & 63, wid = tid >> 6;
    int c = lane & 15, g = lane >> 4;

    // XCD-chunked swizzle: 512 blocks, 64 per XCD -> each XCD sees 2 bh values.
    int sw = (blockIdx.x & 7) * 64 + (blockIdx.x >> 3);
    int bh = sw >> 5, b = bh >> 3, h = bh & 7;
    int q0 = (sw & 31) * 128;

    const __bf16* Qb = Q + (size_t)bh * 4096 * 64;
    const __bf16* Kb = K + (size_t)bh * 4096 * 64;
    const __bf16* Vb = Vt + (size_t)bh * 64 * 4096;
    int qw = q0 + wid * 32;

    // mask int -> additive float -> LDS (fused maskprep)
    {
        const int4* msrc = (const int4*)(mask + (size_t)b * 4096);
        float4* mdst = (float4*)(smem + 57344);
#pragma unroll
        for (int p = 0; p < 4; ++p) {
            int4 m = msrc[p * 256 + tid];
            float4 f = {m.x ? 0.f : -1e30f, m.y ? 0.f : -1e30f,
                        m.z ? 0.f : -1e30f, m.w ? 0.f : -1e30f};
            mdst[p * 256 + tid] = f;
        }
    }

    // Q fragments (B operand of S^T = K Q^T)
    bf16x8 qf[2][2];
#pragma unroll
    for (int nq = 0; nq < 2; ++nq)
#pragma unroll
        for (int ks = 0; ks < 2; ++ks)
            qf[nq][ks] = *(const bf16x8*)(Qb + (size_t)(qw + nq * 16 + c) * 64 +
                                          g * 8 + ks * 32);

    // staging bases (pre-swizzled global source, linear LDS dest)
    int rowp = tid >> 3;                               // 0..31
    int jlow = ((tid & 7) << 4) ^ ((rowp & 7) << 4);   // p-independent
    const char* kB0 = (const char*)Kb + rowp * 128 + jlow;
    const char* kB1 = (const char*)Kb + (32 + rowp) * 128 + jlow;
    const char* vB0 = (const char*)Vb + rowp * 8192 + jlow;
    const char* vB1 = (const char*)Vb + (32 + rowp) * 8192 + jlow;
    int woff = (tid >> 6) * 1024;

#define STAGE(t)                                                              \
    {                                                                         \
        int uk_ = (t) % 3, uv_ = (t) & 3;                                     \
        size_t ko_ = (size_t)(t) * 8192, vo_ = (size_t)(t) * 128;             \
        gload_lds16(smem + uk_ * 8192 + woff, kB0 + ko_);                     \
        gload_lds16(smem + uk_ * 8192 + 4096 + woff, kB1 + ko_);              \
        gload_lds16(smem + 24576 + uv_ * 8192 + woff, vB0 + vo_);             \
        gload_lds16(smem + 24576 + uv_ * 8192 + 4096 + woff, vB1 + vo_);      \
    }

    f32x4 zero = {0.f, 0.f, 0.f, 0.f};
    f32x4 acc[4][2];  // acc[hd-tile][q-tile]: row=hd, col=q
#pragma unroll
    for (int i = 0; i < 4; ++i)
#pragma unroll
        for (int j = 0; j < 2; ++j) acc[i][j] = zero;
    f32x4 rsum4[2] = {zero, zero};  // per-lane partial row sums

    // S^T(t) = mask + K(t) Q^T, into s (mask seeds the MFMA accumulator)
    auto QKT = [&](int t, f32x4(&s)[4][2]) {
        const char* Ktc = smem + (t % 3) * 8192;
#pragma unroll
        for (int mt = 0; mt < 4; ++mt) {
            f32x4 mv =
                *(const f32x4*)(smem + 57344 + t * 256 + mt * 64 + g * 16);
            s[mt][0] = mv;
            s[mt][1] = mv;
        }
        __builtin_amdgcn_s_setprio(1);
#pragma unroll
        for (int ks = 0; ks < 2; ++ks) {
            bf16x8 kf[4];
#pragma unroll
            for (int mt = 0; mt < 4; ++mt)
                kf[mt] = frag_ld(Ktc, mt * 16 + c, g * 16 + ks * 64);
#pragma unroll
            for (int mt = 0; mt < 4; ++mt)
#pragma unroll
                for (int nq = 0; nq < 2; ++nq)
                    s[mt][nq] = MFMA16(kf[mt], qf[nq][ks], s[mt][nq]);
        }
        __builtin_amdgcn_s_setprio(0);
    };

    // softmax(s) in-register + PV(t): x^T += V(t)^T P^T
    auto SMPV = [&](int t, f32x4(&s)[4][2]) {
        const char* Vtc = smem + 24576 + (t & 3) * 8192;
        unsigned int pku[4][2][2];
#pragma unroll
        for (int mt = 0; mt < 4; ++mt)
#pragma unroll
            for (int nq = 0; nq < 2; ++nq) {
                f32x4 p;
#pragma unroll
                for (int j = 0; j < 4; ++j)
                    p[j] = __builtin_amdgcn_exp2f(s[mt][nq][j]);
                rsum4[nq] += p;
                bf16x4 pw = {(__bf16)p[0], (__bf16)p[1], (__bf16)p[2],
                             (__bf16)p[3]};
                u32x2 u2 = __builtin_bit_cast(u32x2, pw);
                pku[mt][nq][0] = u2.x;
                pku[mt][nq][1] = u2.y;
            }
#pragma unroll
        for (int ks2 = 0; ks2 < 2; ++ks2) {
            bf16x8 vf[4];
#pragma unroll
            for (int mh = 0; mh < 4; ++mh)
                vf[mh] = frag_ld(Vtc, mh * 16 + c, g * 16 + ks2 * 64);
            bf16x8 pf[2];
#pragma unroll
            for (int nq = 0; nq < 2; ++nq) {
                unsigned int a0 = pku[2 * ks2][nq][0];
                unsigned int a1 = pku[2 * ks2][nq][1];
                unsigned int b0 = pku[2 * ks2 + 1][nq][0];
                unsigned int b1 = pku[2 * ks2 + 1][nq][1];
                asm("v_permlane32_swap_b32 %0, %1" : "+v"(a0), "+v"(b0));
                asm("v_permlane32_swap_b32 %0, %1" : "+v"(a1), "+v"(b1));
                asm("v_permlane16_swap_b32 %0, %1" : "+v"(a0), "+v"(b0));
                asm("v_permlane16_swap_b32 %0, %1" : "+v"(a1), "+v"(b1));
                u32x4 pv = {a0, a1, b0, b1};
                pf[nq] = __builtin_bit_cast(bf16x8, pv);
            }
            __builtin_amdgcn_s_setprio(1);
#pragma unroll
            for (int mh = 0; mh < 4; ++mh)
#pragma unroll
                for (int nq = 0; nq < 2; ++nq)
                    acc[mh][nq] = MFMA16(vf[mh], pf[nq], acc[mh][nq]);
            __builtin_amdgcn_s_setprio(0);
        }
    };

    // drain prologue vmem (mask/Q loads) + LDS mask writes, then prime pipeline
    asm volatile("s_waitcnt vmcnt(0) lgkmcnt(0)" ::: "memory");
    __builtin_amdgcn_sched_barrier(0);
    STAGE(0);
    STAGE(1);
    STAGE(2);
    asm volatile("s_waitcnt vmcnt(8)" ::: "memory");  // tile 0 landed
    __builtin_amdgcn_s_barrier();
    __builtin_amdgcn_sched_barrier(0);

    f32x4 sA[4][2], sB[4][2];
    QKT(0, sA);

#pragma unroll 1
    for (int tt = 0; tt < 32; ++tt) {
        int t0 = 2 * tt, t1 = 2 * tt + 1;
        // ---- iter t0: prev in sA, next into sB ----
        asm volatile("s_waitcnt vmcnt(0)" ::: "memory");
        __builtin_amdgcn_s_barrier();
        __builtin_amdgcn_sched_barrier(0);
        if (t0 <= 60) STAGE(t0 + 3);
        if (t0 < 63) QKT(t0 + 1, sB);
        SMPV(t0, sA);
        // ---- iter t1: prev in sB, next into sA ----
        asm volatile("s_waitcnt vmcnt(0)" ::: "memory");
        __builtin_amdgcn_s_barrier();
        __builtin_amdgcn_sched_barrier(0);
        if (t1 <= 60) STAGE(t1 + 3);
        if (t1 < 63) QKT(t1 + 1, sA);
        SMPV(t1, sB);
    }
#undef STAGE

    // final L reduce: horizontal sum + 2 shfl over g-groups
    float rl[2];
#pragma unroll
    for (int nq = 0; nq < 2; ++nq) {
        float r = (rsum4[nq][0] + rsum4[nq][1]) + (rsum4[nq][2] + rsum4[nq][3]);
        r += __shfl_xor(r, 16, 64);
        r += __shfl_xor(r, 32, 64);
        rl[nq] = 1.0f / r;
    }

    __syncthreads();  // full drain before reusing LDS for O staging

    // normalize, stage O tile [128 q][64 hd] in smem (pitch 144), coalesced store
    char* Pw = smem + wid * 4608;
#pragma unroll
    for (int mh = 0; mh < 4; ++mh)
#pragma unroll
        for (int nq = 0; nq < 2; ++nq) {
            bf16x4 o;
#pragma unroll
            for (int j = 0; j < 4; ++j) o[j] = (__bf16)(acc[mh][nq][j] * rl[nq]);
            *(bf16x4*)(Pw + (nq * 16 + c) * 144 + mh * 32 + g * 8) = o;
        }
    __syncthreads();
#pragma unroll
    for (int p = 0; p < 4; ++p) {
        int i = p * 4096 + tid * 16;
        int row = i >> 7, colb = i & 127;
        bf16x8 v = *(const bf16x8*)(smem + row * 144 + colb);
        *(bf16x8*)(O + ((size_t)(b * 4096 + q0 + row)) * 512 + h * 64 +
                   colb / 2) = v;
    }
}

extern "C" void kernel_launch(void* const* d_in, const int* in_sizes, int n_in,
                              void* d_out, int out_size, void* d_ws,
                              size_t ws_size, hipStream_t stream) {
    const float* query = (const float*)d_in[0];
    const float* key = (const float*)d_in[1];
    const float* value = (const float*)d_in[2];
    const int* mask = (const int*)d_in[3];
    const float* Wq = (const float*)d_in[4];
    const float* bq = (const float*)d_in[5];
    const float* Wk = (const float*)d_in[6];
    const float* bk = (const float*)d_in[7];
    const float* Wv = (const float*)d_in[8];
    const float* bv = (const float*)d_in[9];
    const float* Wo = (const float*)d_in[10];
    const float* bo = (const float*)d_in[11];

    char* ws = (char*)d_ws;
    __bf16* Wt = (__bf16*)(ws + 25165824);        // 2097152 B
    __bf16* Qb = (__bf16*)(ws + 27262976);        // 8388608 B
    __bf16* Kb = (__bf16*)(ws + 35651584);        // 8388608 B
    __bf16* Vtb = (__bf16*)(ws + 44040192);       // 8388608 B
    __bf16* Ob = (__bf16*)(ws + 52428800);        // 8388608 B

    wtrans<<<dim3(16, 16, 4), 256, 0, stream>>>(Wq, Wk, Wv, Wo, Wt);
    gemm_qkv<true><<<dim3(64, 4, 3), 256, 0, stream>>>(
        query, key, value, nullptr, Wt, bq, bk, bv, Qb, Kb, Vtb, 0, nullptr);
    attn_fa<<<dim3(512), 256, 0, stream>>>(Qb, Kb, Vtb, mask, Ob);
    gemm_qkv<false><<<dim3(64, 4, 1), 256, 0, stream>>>(
        nullptr, nullptr, nullptr, Ob, Wt + 3 * 262144, bo, bo, bo, Qb, Kb,
        Vtb, 3, (float*)d_out);
}